// Round 3
// baseline (147.680 us; speedup 1.0000x reference)
//
#include <hip/hip_runtime.h>

#define BB 4
#define SS 256
#define DD 768
#define DEPC 100
#define HH 12
#define DKK 64

// ---------- K1: u_t[h][p] = sum_d W_e[p][h*64+d] * w_rel[d]  (transposed) ----------
__global__ __launch_bounds__(256) void k_u(const float* __restrict__ W_e,
                                           const float* __restrict__ w_rel,
                                           float* __restrict__ u_t) {
    int e = blockIdx.x * 256 + threadIdx.x;
    if (e >= DEPC * HH) return;
    int p = e / HH, h = e % HH;
    const float4* we = (const float4*)(W_e + p * DD + h * DKK);
    const float4* wr = (const float4*)w_rel;
    float acc = 0.f;
#pragma unroll
    for (int c = 0; c < DKK / 4; ++c) {
        float4 a = we[c], b = wr[c];
        acc += a.x * b.x + a.y * b.y + a.z * b.z + a.w * b.w;
    }
    u_t[h * DEPC + p] = acc;
}

// ---------- K2: V = token @ W_v  (1024x768 @ 768x768, fp32 tiled) ----------
#define TM 32
#define TN 64
#define TKK 16
__global__ __launch_bounds__(256) void k_v(const float* __restrict__ A,
                                           const float* __restrict__ Bm,
                                           float* __restrict__ C) {
    __shared__ float As[TKK][TM + 4];
    __shared__ float Bs[TKK][TN];
    int t = threadIdx.x;
    int tx = t & 15, ty = t >> 4;
    int r0 = blockIdx.x * TM, c0 = blockIdx.y * TN;
    float acc[2][4] = {};
    for (int k0 = 0; k0 < DD; k0 += TKK) {
        As[tx][ty]      = A[(r0 + ty) * DD + k0 + tx];
        As[tx][ty + 16] = A[(r0 + ty + 16) * DD + k0 + tx];
        int kb = t >> 6, cb = t & 63;
#pragma unroll
        for (int q = 0; q < 4; ++q)
            Bs[kb + 4 * q][cb] = Bm[(k0 + kb + 4 * q) * DD + c0 + cb];
        __syncthreads();
#pragma unroll
        for (int kk = 0; kk < TKK; ++kk) {
            float a0 = As[kk][2 * ty], a1 = As[kk][2 * ty + 1];
            float4 b = *(const float4*)&Bs[kk][4 * tx];
            acc[0][0] += a0 * b.x; acc[0][1] += a0 * b.y;
            acc[0][2] += a0 * b.z; acc[0][3] += a0 * b.w;
            acc[1][0] += a1 * b.x; acc[1][1] += a1 * b.y;
            acc[1][2] += a1 * b.z; acc[1][3] += a1 * b.w;
        }
        __syncthreads();
    }
#pragma unroll
    for (int m = 0; m < 2; ++m) {
        float4 v = make_float4(acc[m][0], acc[m][1], acc[m][2], acc[m][3]);
        *(float4*)&C[(size_t)(r0 + 2 * ty + m) * DD + c0 + 4 * tx] = v;
    }
}

// ---------- K3: scores = mask ? relu(E . u) : -1e6 ----------
// 64-row swizzled LDS chunks; lane=row, wave=3-head slice, u via scalar loads.
__global__ __launch_bounds__(256) void k_sc(const float* __restrict__ edge,
                                            const int* __restrict__ mask,
                                            const float* __restrict__ ut,
                                            float* __restrict__ scores) {
    __shared__ float buf[64 * 128];  // 32 KB, [r][32 float4] XOR-swizzled
    float4* buf4 = (float4*)buf;
    int t = threadIdx.x;
    int i = blockIdx.x, b = blockIdx.y;
    int r = t & 63, rx = r & 7;
    int hbase = __builtin_amdgcn_readfirstlane((t >> 6) * 3);  // wave-uniform
    const float* uw = ut + hbase * DEPC;                        // scalar-load base
    const float4* panel4 = (const float4*)(edge + (size_t)(b * SS + i) * SS * DEPC);
    const int* mrow = mask + (size_t)(b * SS + i) * SS;

    float4 v[7];
    // stage chunk 0: contiguous float4 stream (1600 of them)
#pragma unroll
    for (int k = 0; k < 7; ++k) {
        int idx = t + 256 * k;
        if (idx < 1600) v[k] = panel4[idx];
    }
#pragma unroll
    for (int k = 0; k < 7; ++k) {
        int idx = t + 256 * k;
        if (idx < 1600) {
            int rr = idx / 25, cc = idx - rr * 25;
            buf4[(rr << 5) | (cc ^ (rr & 7))] = v[k];
        }
    }
    __syncthreads();

    for (int c = 0; c < 4; ++c) {
        // prefetch next chunk into registers (latency hides under compute)
        if (c < 3) {
#pragma unroll
            for (int k = 0; k < 7; ++k) {
                int idx = t + 256 * k;
                if (idx < 1600) v[k] = panel4[(c + 1) * 1600 + idx];
            }
        }
        float a0 = 0.f, a1 = 0.f, a2 = 0.f;
#pragma unroll
        for (int c4 = 0; c4 < 25; ++c4) {
            float4 e4 = buf4[(r << 5) | (c4 ^ rx)];
            const float* ep = (const float*)&e4;
#pragma unroll
            for (int m = 0; m < 4; ++m) {
                int p = 4 * c4 + m;
                float ev = ep[m];
                a0 += ev * uw[p];
                a1 += ev * uw[DEPC + p];
                a2 += ev * uw[2 * DEPC + p];
            }
        }
        int j = c * 64 + r;
        int mk = mrow[j];
        float s0 = mk ? fmaxf(a0, 0.f) : -1e6f;
        float s1 = mk ? fmaxf(a1, 0.f) : -1e6f;
        float s2 = mk ? fmaxf(a2, 0.f) : -1e6f;
        size_t sb = (((size_t)b * HH + hbase) * SS + i) * SS + j;
        scores[sb] = s0;
        scores[sb + (size_t)SS * SS] = s1;
        scores[sb + 2 * (size_t)SS * SS] = s2;
        __syncthreads();  // all waves done reading buf
        if (c < 3) {
#pragma unroll
            for (int k = 0; k < 7; ++k) {
                int idx = t + 256 * k;
                if (idx < 1600) {
                    int rr = idx / 25, cc = idx - rr * 25;
                    buf4[(rr << 5) | (cc ^ (rr & 7))] = v[k];
                }
            }
        }
        __syncthreads();  // buf ready for next chunk
    }
}

// ---------- K4: softmax over j + ctx = P@V + relu(token+ctx) ----------
#define GG 4
__global__ __launch_bounds__(256) void k_ctx(const float* __restrict__ scores,
                                             const float* __restrict__ V,
                                             const float* __restrict__ token,
                                             float* __restrict__ out) {
    __shared__ float sc[GG][HH][SS];  // 48 KB
    int t = threadIdx.x, b = blockIdx.y, i0 = blockIdx.x * GG;
    for (int idx = t; idx < GG * HH * (SS / 4); idx += 256) {
        int jc = idx & 63, rr = idx >> 6;
        int g = rr / HH, h = rr % HH;
        float4 v = *(const float4*)(scores + (((size_t)b * HH + h) * SS + (i0 + g)) * SS + 4 * jc);
        *(float4*)&sc[g][h][4 * jc] = v;
    }
    __syncthreads();
    int lane = t & 63, w = t >> 6;
    for (int rr = w; rr < GG * HH; rr += 4) {
        int g = rr / HH, h = rr % HH;
        float x0 = sc[g][h][lane],       x1 = sc[g][h][lane + 64];
        float x2 = sc[g][h][lane + 128], x3 = sc[g][h][lane + 192];
        float m = fmaxf(fmaxf(x0, x1), fmaxf(x2, x3));
#pragma unroll
        for (int o = 32; o > 0; o >>= 1) m = fmaxf(m, __shfl_xor(m, o, 64));
        x0 = __expf(x0 - m); x1 = __expf(x1 - m);
        x2 = __expf(x2 - m); x3 = __expf(x3 - m);
        float s = x0 + x1 + x2 + x3;
#pragma unroll
        for (int o = 32; o > 0; o >>= 1) s += __shfl_xor(s, o, 64);
        float inv = 1.0f / s;
        sc[g][h][lane] = x0 * inv;       sc[g][h][lane + 64] = x1 * inv;
        sc[g][h][lane + 128] = x2 * inv; sc[g][h][lane + 192] = x3 * inv;
    }
    __syncthreads();
    float acc[3][GG] = {};
    for (int j0 = 0; j0 < SS; j0 += 4) {
#pragma unroll
        for (int a = 0; a < 3; ++a) {
            int hd = t + 256 * a;
            int h = hd >> 6;
            float v0 = V[(size_t)(b * SS + j0) * DD + hd];
            float v1 = V[(size_t)(b * SS + j0 + 1) * DD + hd];
            float v2 = V[(size_t)(b * SS + j0 + 2) * DD + hd];
            float v3 = V[(size_t)(b * SS + j0 + 3) * DD + hd];
#pragma unroll
            for (int g = 0; g < GG; ++g) {
                float4 p = *(const float4*)&sc[g][h][j0];
                acc[a][g] += p.x * v0 + p.y * v1 + p.z * v2 + p.w * v3;
            }
        }
    }
#pragma unroll
    for (int a = 0; a < 3; ++a) {
        int hd = t + 256 * a;
#pragma unroll
        for (int g = 0; g < GG; ++g) {
            size_t o = (size_t)(b * SS + i0 + g) * DD + hd;
            out[o] = fmaxf(token[o] + acc[a][g], 0.f);
        }
    }
}

extern "C" void kernel_launch(void* const* d_in, const int* in_sizes, int n_in,
                              void* d_out, int out_size, void* d_ws, size_t ws_size,
                              hipStream_t stream) {
    const float* token = (const float*)d_in[0];
    const float* edge  = (const float*)d_in[1];
    const int*   mask  = (const int*)d_in[2];
    const float* W_v   = (const float*)d_in[3];
    const float* W_e   = (const float*)d_in[4];
    const float* w_rel = (const float*)d_in[5];
    float* out = (float*)d_out;

    char* ws = (char*)d_ws;
    float* u_t    = (float*)(ws);                                   // 4.8 KB
    float* V      = (float*)(ws + 8192);                            // 3.15 MB
    float* scores = (float*)(ws + 8192 + (size_t)BB * SS * DD * 4); // 12.6 MB

    hipLaunchKernelGGL(k_u,   dim3((DEPC * HH + 255) / 256), dim3(256), 0, stream, W_e, w_rel, u_t);
    hipLaunchKernelGGL(k_v,   dim3((BB * SS) / TM, DD / TN), dim3(256), 0, stream, token, W_v, V);
    hipLaunchKernelGGL(k_sc,  dim3(SS, BB),                  dim3(256), 0, stream, edge, mask, u_t, scores);
    hipLaunchKernelGGL(k_ctx, dim3(SS / GG, BB),             dim3(256), 0, stream, scores, V, token, out);
}

// Round 4
// 115.234 us; speedup vs baseline: 1.2816x; 1.2816x over previous
//
#include <hip/hip_runtime.h>
#include <stdint.h>

#define BB 4
#define SS 256
#define DD 768
#define DEPC 100
#define HH 12
#define DKK 64

// ---------- K1: u_t[h][p] = sum_d W_e[p][h*64+d] * w_rel[d]  (transposed) ----------
__global__ __launch_bounds__(256) void k_u(const float* __restrict__ W_e,
                                           const float* __restrict__ w_rel,
                                           float* __restrict__ u_t) {
    int e = blockIdx.x * 256 + threadIdx.x;
    if (e >= DEPC * HH) return;
    int p = e / HH, h = e % HH;
    const float4* we = (const float4*)(W_e + p * DD + h * DKK);
    const float4* wr = (const float4*)w_rel;
    float acc = 0.f;
#pragma unroll
    for (int c = 0; c < DKK / 4; ++c) {
        float4 a = we[c], b = wr[c];
        acc += a.x * b.x + a.y * b.y + a.z * b.z + a.w * b.w;
    }
    u_t[h * DEPC + p] = acc;
}

// ---------- K2: V = token @ W_v  (1024x768 @ 768x768, fp32 tiled) ----------
#define TM 32
#define TN 64
#define TKK 16
__global__ __launch_bounds__(256) void k_v(const float* __restrict__ A,
                                           const float* __restrict__ Bm,
                                           float* __restrict__ C) {
    __shared__ float As[TKK][TM + 4];
    __shared__ float Bs[TKK][TN];
    int t = threadIdx.x;
    int tx = t & 15, ty = t >> 4;
    int r0 = blockIdx.x * TM, c0 = blockIdx.y * TN;
    float acc[2][4] = {};
    for (int k0 = 0; k0 < DD; k0 += TKK) {
        As[tx][ty]      = A[(r0 + ty) * DD + k0 + tx];
        As[tx][ty + 16] = A[(r0 + ty + 16) * DD + k0 + tx];
        int kb = t >> 6, cb = t & 63;
#pragma unroll
        for (int q = 0; q < 4; ++q)
            Bs[kb + 4 * q][cb] = Bm[(k0 + kb + 4 * q) * DD + c0 + cb];
        __syncthreads();
#pragma unroll
        for (int kk = 0; kk < TKK; ++kk) {
            float a0 = As[kk][2 * ty], a1 = As[kk][2 * ty + 1];
            float4 b = *(const float4*)&Bs[kk][4 * tx];
            acc[0][0] += a0 * b.x; acc[0][1] += a0 * b.y;
            acc[0][2] += a0 * b.z; acc[0][3] += a0 * b.w;
            acc[1][0] += a1 * b.x; acc[1][1] += a1 * b.y;
            acc[1][2] += a1 * b.z; acc[1][3] += a1 * b.w;
        }
        __syncthreads();
    }
#pragma unroll
    for (int m = 0; m < 2; ++m) {
        float4 v = make_float4(acc[m][0], acc[m][1], acc[m][2], acc[m][3]);
        *(float4*)&C[(size_t)(r0 + 2 * ty + m) * DD + c0 + 4 * tx] = v;
    }
}

// ---------- K3: scores = mask ? relu(E . u) : -1e6 ----------
// One block per 64-row j-chunk. Linear LDS (stride 100 ≡ 4 mod 32: self-staggered,
// conflict-free). Stage via global_load_lds (no VGPR round-trip, nothing to spill).
__global__ __launch_bounds__(256) void k_sc(const float* __restrict__ edge,
                                            const int* __restrict__ mask,
                                            const float* __restrict__ ut,
                                            float* __restrict__ scores) {
    __shared__ float buf[64 * DEPC];  // 25.6 KB
    int t = threadIdx.x;
    int jc = blockIdx.x & 3;
    int i  = blockIdx.x >> 2;
    int b  = blockIdx.y;
    int lane = t & 63, w = t >> 6;

    const float* src = edge + (size_t)((b * SS + i) * SS + jc * 64) * DEPC;
    // 64 rows x 100 floats = 1600 float4; one wave-call stages 64 float4 = 1 KB
    for (int call = w; call < 25; call += 4) {
        __builtin_amdgcn_global_load_lds(
            (__attribute__((address_space(1))) const void*)(src + (size_t)(call * 64 + lane) * 4),
            (__attribute__((address_space(3))) void*)(buf + call * 256),
            16, 0, 0);
    }
    __syncthreads();

    int hbase = __builtin_amdgcn_readfirstlane(w * 3);  // 3 heads per wave
    const float* uw = ut + hbase * DEPC;                // wave-uniform -> s_load
    const float4* row4 = (const float4*)(buf + lane * DEPC);
    float a0 = 0.f, a1 = 0.f, a2 = 0.f;
#pragma unroll
    for (int c4 = 0; c4 < 25; ++c4) {
        float4 e4 = row4[c4];
        const float* ep = (const float*)&e4;
#pragma unroll
        for (int m = 0; m < 4; ++m) {
            int p = 4 * c4 + m;
            a0 += ep[m] * uw[p];
            a1 += ep[m] * uw[DEPC + p];
            a2 += ep[m] * uw[2 * DEPC + p];
        }
    }
    int j = jc * 64 + lane;
    int mk = mask[(size_t)(b * SS + i) * SS + j];
    size_t sb = (((size_t)b * HH + hbase) * SS + i) * SS + j;
    scores[sb]                       = mk ? fmaxf(a0, 0.f) : -1e6f;
    scores[sb + (size_t)SS * SS]     = mk ? fmaxf(a1, 0.f) : -1e6f;
    scores[sb + 2 * (size_t)SS * SS] = mk ? fmaxf(a2, 0.f) : -1e6f;
}

// ---------- K4: softmax over j + ctx = P@V + relu(token+ctx) ----------
#define GG 4
__global__ __launch_bounds__(256) void k_ctx(const float* __restrict__ scores,
                                             const float* __restrict__ V,
                                             const float* __restrict__ token,
                                             float* __restrict__ out) {
    __shared__ float sc[GG][HH][SS];  // 48 KB
    int t = threadIdx.x, b = blockIdx.y, i0 = blockIdx.x * GG;
    for (int idx = t; idx < GG * HH * (SS / 4); idx += 256) {
        int jc = idx & 63, rr = idx >> 6;
        int g = rr / HH, h = rr % HH;
        float4 v = *(const float4*)(scores + (((size_t)b * HH + h) * SS + (i0 + g)) * SS + 4 * jc);
        *(float4*)&sc[g][h][4 * jc] = v;
    }
    __syncthreads();
    int lane = t & 63, w = t >> 6;
    for (int rr = w; rr < GG * HH; rr += 4) {
        int g = rr / HH, h = rr % HH;
        float x0 = sc[g][h][lane],       x1 = sc[g][h][lane + 64];
        float x2 = sc[g][h][lane + 128], x3 = sc[g][h][lane + 192];
        float m = fmaxf(fmaxf(x0, x1), fmaxf(x2, x3));
#pragma unroll
        for (int o = 32; o > 0; o >>= 1) m = fmaxf(m, __shfl_xor(m, o, 64));
        x0 = __expf(x0 - m); x1 = __expf(x1 - m);
        x2 = __expf(x2 - m); x3 = __expf(x3 - m);
        float s = x0 + x1 + x2 + x3;
#pragma unroll
        for (int o = 32; o > 0; o >>= 1) s += __shfl_xor(s, o, 64);
        float inv = 1.0f / s;
        sc[g][h][lane] = x0 * inv;       sc[g][h][lane + 64] = x1 * inv;
        sc[g][h][lane + 128] = x2 * inv; sc[g][h][lane + 192] = x3 * inv;
    }
    __syncthreads();
    float acc[3][GG] = {};
    for (int j0 = 0; j0 < SS; j0 += 4) {
#pragma unroll
        for (int a = 0; a < 3; ++a) {
            int hd = t + 256 * a;
            int h = hd >> 6;
            float v0 = V[(size_t)(b * SS + j0) * DD + hd];
            float v1 = V[(size_t)(b * SS + j0 + 1) * DD + hd];
            float v2 = V[(size_t)(b * SS + j0 + 2) * DD + hd];
            float v3 = V[(size_t)(b * SS + j0 + 3) * DD + hd];
#pragma unroll
            for (int g = 0; g < GG; ++g) {
                float4 p = *(const float4*)&sc[g][h][j0];
                acc[a][g] += p.x * v0 + p.y * v1 + p.z * v2 + p.w * v3;
            }
        }
    }
#pragma unroll
    for (int a = 0; a < 3; ++a) {
        int hd = t + 256 * a;
#pragma unroll
        for (int g = 0; g < GG; ++g) {
            size_t o = (size_t)(b * SS + i0 + g) * DD + hd;
            out[o] = fmaxf(token[o] + acc[a][g], 0.f);
        }
    }
}

extern "C" void kernel_launch(void* const* d_in, const int* in_sizes, int n_in,
                              void* d_out, int out_size, void* d_ws, size_t ws_size,
                              hipStream_t stream) {
    const float* token = (const float*)d_in[0];
    const float* edge  = (const float*)d_in[1];
    const int*   mask  = (const int*)d_in[2];
    const float* W_v   = (const float*)d_in[3];
    const float* W_e   = (const float*)d_in[4];
    const float* w_rel = (const float*)d_in[5];
    float* out = (float*)d_out;

    char* ws = (char*)d_ws;
    float* u_t    = (float*)(ws);                                   // 4.8 KB
    float* V      = (float*)(ws + 8192);                            // 3.15 MB
    float* scores = (float*)(ws + 8192 + (size_t)BB * SS * DD * 4); // 12.6 MB

    hipLaunchKernelGGL(k_u,   dim3((DEPC * HH + 255) / 256), dim3(256), 0, stream, W_e, w_rel, u_t);
    hipLaunchKernelGGL(k_v,   dim3((BB * SS) / TM, DD / TN), dim3(256), 0, stream, token, W_v, V);
    hipLaunchKernelGGL(k_sc,  dim3(SS * 4, BB),              dim3(256), 0, stream, edge, mask, u_t, scores);
    hipLaunchKernelGGL(k_ctx, dim3(SS / GG, BB),             dim3(256), 0, stream, scores, V, token, out);
}